// Round 13
// baseline (342.519 us; speedup 1.0000x reference)
//
#include <hip/hip_runtime.h>
#include <hip/hip_bf16.h>

#define NROWS 16384
#define DIM   1024
#define NT    8                          // K-tiles (1024 / 128 i8)
#define NTILE 128                        // 128-row tiles per dim
#define NBLK  (NTILE * (NTILE + 1) / 2)  // 8256 upper-tri blocks (= 8*1032)

typedef int i32x4 __attribute__((ext_vector_type(4)));

// monotone float -> uint key (order-preserving), so atomicMax works on floats
__device__ __forceinline__ unsigned fkey(float f) {
    unsigned u = __float_as_uint(f);
    return (u & 0x80000000u) ? ~u : (u | 0x80000000u);
}
__device__ __forceinline__ float funkey(unsigned k) {
    unsigned u = (k & 0x80000000u) ? (k & 0x7fffffffu) : ~k;
    return __uint_as_float(u);
}

// One block per row: fp32 norm, quantize q = round(127*x/||x||) (i8), store
// packed; also per-row inverse quantized norm s = 1/||q|| so sim is the EXACT
// cosine of the integer vectors (removes norm quantization error).
__global__ void normalize_rows(const float* __restrict__ x,
                               signed char* __restrict__ xq,
                               float* __restrict__ sinv,
                               unsigned* __restrict__ rowmax) {
    const int row = blockIdx.x;
    const int t = threadIdx.x;                      // 256 threads, 1 float4 each
    const float4 v = ((const float4*)(x + (size_t)row * DIM))[t];
    float ss = v.x * v.x + v.y * v.y + v.z * v.z + v.w * v.w;
#pragma unroll
    for (int off = 32; off > 0; off >>= 1) ss += __shfl_xor(ss, off);
    __shared__ float wss[4];
    __shared__ int   wqs[4];
    if ((t & 63) == 0) wss[t >> 6] = ss;
    __syncthreads();
    const float tot = wss[0] + wss[1] + wss[2] + wss[3];
    const float scale = 127.0f / fmaxf(sqrtf(tot), 1e-12f);
    int qx = __float2int_rn(v.x * scale);
    int qy = __float2int_rn(v.y * scale);
    int qz = __float2int_rn(v.z * scale);
    int qw = __float2int_rn(v.w * scale);
    qx = max(-127, min(127, qx)); qy = max(-127, min(127, qy));
    qz = max(-127, min(127, qz)); qw = max(-127, min(127, qw));
    const int p = (qx & 0xff) | ((qy & 0xff) << 8) | ((qz & 0xff) << 16) | ((qw & 0xff) << 24);
    ((int*)(xq + (size_t)row * DIM))[t] = p;
    int qs = qx * qx + qy * qy + qz * qz + qw * qw;
#pragma unroll
    for (int off = 32; off > 0; off >>= 1) qs += __shfl_xor(qs, off);
    if ((t & 63) == 0) wqs[t >> 6] = qs;
    __syncthreads();
    if (t == 0) {
        const int qtot = max(wqs[0] + wqs[1] + wqs[2] + wqs[3], 1);
        sinv[row] = 1.0f / sqrtf((float)qtot);
        rowmax[row] = 0u;
    }
}

// ---- simmax: i8 on the m97 128^2 single-buffer structure ----
// 128x128 tile, K-tile=128 i8 (rows are 128 B -- byte-identical LDS geometry,
// swizzle and staging to the verified bf16 R11 kernel), 256 threads (2x2
// waves, 64x64 out/wave), SINGLE 32 KiB LDS buffer, plain 2-barrier K-loop.
// __launch_bounds__(256,4): ~90 VGPR -> 4 waves/SIMD = 4 blocks/CU (LDS
// 4x32KB=128KiB) -- cross-block overlap hides the per-tile staging drain
// (m97/m114 mechanism; the 256^2 kernels were stuck at 1 block/CU).

__global__ __launch_bounds__(256, 4)
void simmax_kernel(const signed char* __restrict__ xq,
                   const float* __restrict__ sinv,
                   unsigned* __restrict__ rowmax) {
    // T1: bijective XCD-chunked swizzle (8256 = 8 * 1032)
    const int bid = blockIdx.x;
    int rem = (bid & 7) * (NBLK / 8) + (bid >> 3);
    int it = 0;
    while (rem >= NTILE - it) { rem -= NTILE - it; ++it; }
    const int jt = it + rem;
    const bool diag = (jt == it);
    const int rowBase = it * 128;
    const int colBase = jt * 128;

    __shared__ __align__(16) char lds[2][128][128];  // [A/B][row][128 B] = 32 KiB

    const int t    = threadIdx.x;                    // 256 = 4 waves
    const int lane = t & 63;
    const int wid  = t >> 6;
    const int wr2  = wid >> 1;     // 0..1 (M)
    const int wc2  = wid & 1;      // 0..1 (N)
    const int l15  = lane & 15;
    const int hi   = lane >> 4;

    // staging: chunk c = j*256 + t (j=0..7); op = c>>10 (A/B); cc = c&1023;
    // row = cc>>3, ch = cc&7. LDS dest LINEAR (c*16 B); SOURCE chunk
    // pre-swizzled (ch ^ (row&7)) so the swizzled ds_read finds it (rule #21).
    const signed char* srcp[8];
#pragma unroll
    for (int j = 0; j < 8; ++j) {
        const int c   = j * 256 + t;
        const int op  = c >> 10;
        const int cc  = c & 1023;
        const int row = cc >> 3;
        const int ch  = cc & 7;
        const int gr  = (op ? colBase : rowBase) + row;
        srcp[j] = xq + (size_t)gr * DIM + (ch ^ (row & 7)) * 16;
    }

    i32x4 acc[4][4];
#pragma unroll
    for (int m = 0; m < 4; ++m)
#pragma unroll
        for (int n = 0; n < 4; ++n)
            acc[m][n] = (i32x4){0, 0, 0, 0};

    char* ldsb = &lds[0][0][0];

    for (int kt = 0; kt < NT; ++kt) {
        __syncthreads();               // previous tile's compute done
#pragma unroll
        for (int j = 0; j < 8; ++j) {
            __builtin_amdgcn_global_load_lds(
                (const __attribute__((address_space(1))) void*)srcp[j],
                (__attribute__((address_space(3))) void*)(ldsb + (j * 256 + wid * 64) * 16),
                16, 0, 0);
            srcp[j] += 128;            // next 128-elem i8 K-tile
        }
        __syncthreads();               // drains vmcnt(0): staged data visible

        i32x4 af[4][2], bf[4][2];
#pragma unroll
        for (int m = 0; m < 4; ++m)
#pragma unroll
            for (int kk = 0; kk < 2; ++kk) {
                const int row = wr2 * 64 + m * 16 + l15;
                const int chn = (kk * 4 + hi) ^ (row & 7);
                af[m][kk] = *(const i32x4*)(&lds[0][0][0] + row * 128 + chn * 16);
            }
#pragma unroll
        for (int n = 0; n < 4; ++n)
#pragma unroll
            for (int kk = 0; kk < 2; ++kk) {
                const int row = wc2 * 64 + n * 16 + l15;
                const int chn = (kk * 4 + hi) ^ (row & 7);
                bf[n][kk] = *(const i32x4*)(&lds[1][0][0] + row * 128 + chn * 16);
            }
#pragma unroll
        for (int m = 0; m < 4; ++m)
#pragma unroll
            for (int n = 0; n < 4; ++n)
#pragma unroll
                for (int kk = 0; kk < 2; ++kk)
                    acc[m][n] = __builtin_amdgcn_mfma_i32_16x16x64_i8(
                        af[m][kk], bf[n][kk], acc[m][n], 0, 0, 0);
    }

    // ---- epilogue: scaled tile max reduction ----
    // C/D layout: col = lane&15, row = (lane>>4)*4 + reg  [m89/m91, dtype-indep]
    const int g  = lane >> 4;
    const int cl = lane & 15;

    // column scales (lane's 4 cols) and row scales (lane's 16 rows)
    float scl_col[4];
#pragma unroll
    for (int n = 0; n < 4; ++n)
        scl_col[n] = sinv[colBase + wc2 * 64 + n * 16 + cl];
    float srow[4][4];
#pragma unroll
    for (int m = 0; m < 4; ++m)
#pragma unroll
        for (int r = 0; r < 4; ++r)
            srow[m][r] = sinv[rowBase + wr2 * 64 + m * 16 + g * 4 + r];

    // row-direction: rowmax[i] takes max_j (s_j * d_ij); s_i applied in finalize
#pragma unroll
    for (int m = 0; m < 4; ++m)
#pragma unroll
        for (int r = 0; r < 4; ++r) {
            const int grow = wr2 * 64 + m * 16 + g * 4 + r;
            float v = -1e30f;
#pragma unroll
            for (int n = 0; n < 4; ++n) {
                const int gcol = wc2 * 64 + n * 16 + cl;
                float f = (float)acc[m][n][r] * scl_col[n];
                if (diag && grow == gcol) f = -1e30f;   // exclude self-sim
                v = fmaxf(v, f);
            }
            v = fmaxf(v, __shfl_xor(v, 1));
            v = fmaxf(v, __shfl_xor(v, 2));
            v = fmaxf(v, __shfl_xor(v, 4));
            v = fmaxf(v, __shfl_xor(v, 8));
            if (cl == 0) atomicMax(rowmax + rowBase + grow, fkey(v));
        }

    // col-direction (transpose contribution): max_i (s_i * d_ij); skip on diag
    if (!diag) {
#pragma unroll
        for (int n = 0; n < 4; ++n) {
            float v = -1e30f;
#pragma unroll
            for (int m = 0; m < 4; ++m)
#pragma unroll
                for (int r = 0; r < 4; ++r)
                    v = fmaxf(v, (float)acc[m][n][r] * srow[m][r]);
            v = fmaxf(v, __shfl_xor(v, 16));
            v = fmaxf(v, __shfl_xor(v, 32));
            if (g == 0) {
                const int gcol = colBase + wc2 * 64 + n * 16 + cl;
                atomicMax(rowmax + gcol, fkey(v));
            }
        }
    }
}

__global__ void finalize_kernel(const unsigned* __restrict__ rowmax,
                                const float* __restrict__ sinv,
                                float* __restrict__ out) {
    const int t = threadIdx.x;
    float s = 0.f;
    for (int r = t; r < NROWS; r += 256) {
        const float m = fminf(sinv[r] * funkey(rowmax[r]), 1.0f);   // cos, clamp
        s += logf(2.0f - 2.0f * m + 1e-8f);
    }
#pragma unroll
    for (int off = 32; off > 0; off >>= 1) s += __shfl_xor(s, off);
    __shared__ float ws[4];
    if ((t & 63) == 0) ws[t >> 6] = s;
    __syncthreads();
    if (t == 0) out[0] = -0.5f * (ws[0] + ws[1] + ws[2] + ws[3]) / (float)NROWS;
}

extern "C" void kernel_launch(void* const* d_in, const int* in_sizes, int n_in,
                              void* d_out, int out_size, void* d_ws, size_t ws_size,
                              hipStream_t stream) {
    const float* x = (const float*)d_in[0];
    signed char* xq = (signed char*)d_ws;                                // 16 MB
    float* sinv = (float*)((char*)d_ws + (size_t)NROWS * DIM);           // 64 KB
    unsigned* rowmax = (unsigned*)((char*)d_ws + (size_t)NROWS * DIM + NROWS * sizeof(float));
    float* out = (float*)d_out;

    normalize_rows<<<NROWS, 256, 0, stream>>>(x, xq, sinv, rowmax);
    simmax_kernel<<<NBLK, 256, 0, stream>>>(xq, sinv, rowmax);
    finalize_kernel<<<1, 256, 0, stream>>>(rowmax, sinv, out);
}

// Round 14
// 245.464 us; speedup vs baseline: 1.3954x; 1.3954x over previous
//
#include <hip/hip_runtime.h>
#include <hip/hip_bf16.h>

#define NROWS 16384
#define DIM   1024
#define NT    8                          // K-tiles (1024 / 128 i8)
#define NTILE 128                        // 128-row tiles per dim
#define NBLK  (NTILE * (NTILE + 1) / 2)  // 8256 upper-tri blocks (= 8*1032)
#define SW    16                         // strip width (16 B-panels = 2MB, L2-fit)

typedef int i32x4 __attribute__((ext_vector_type(4)));

// monotone float -> uint key (order-preserving), so atomicMax works on floats
__device__ __forceinline__ unsigned fkey(float f) {
    unsigned u = __float_as_uint(f);
    return (u & 0x80000000u) ? ~u : (u | 0x80000000u);
}
__device__ __forceinline__ float funkey(unsigned k) {
    unsigned u = (k & 0x80000000u) ? (k & 0x7fffffffu) : ~k;
    return __uint_as_float(u);
}

// One block per row: fp32 norm, quantize q = round(127*x/||x||) (i8), store
// packed; also per-row inverse quantized norm s = 1/||q|| so sim is the EXACT
// cosine of the integer vectors (removes norm quantization error).
__global__ void normalize_rows(const float* __restrict__ x,
                               signed char* __restrict__ xq,
                               float* __restrict__ sinv,
                               unsigned* __restrict__ rowmax) {
    const int row = blockIdx.x;
    const int t = threadIdx.x;                      // 256 threads, 1 float4 each
    const float4 v = ((const float4*)(x + (size_t)row * DIM))[t];
    float ss = v.x * v.x + v.y * v.y + v.z * v.z + v.w * v.w;
#pragma unroll
    for (int off = 32; off > 0; off >>= 1) ss += __shfl_xor(ss, off);
    __shared__ float wss[4];
    __shared__ int   wqs[4];
    if ((t & 63) == 0) wss[t >> 6] = ss;
    __syncthreads();
    const float tot = wss[0] + wss[1] + wss[2] + wss[3];
    const float scale = 127.0f / fmaxf(sqrtf(tot), 1e-12f);
    int qx = __float2int_rn(v.x * scale);
    int qy = __float2int_rn(v.y * scale);
    int qz = __float2int_rn(v.z * scale);
    int qw = __float2int_rn(v.w * scale);
    qx = max(-127, min(127, qx)); qy = max(-127, min(127, qy));
    qz = max(-127, min(127, qz)); qw = max(-127, min(127, qw));
    const int p = (qx & 0xff) | ((qy & 0xff) << 8) | ((qz & 0xff) << 16) | ((qw & 0xff) << 24);
    ((int*)(xq + (size_t)row * DIM))[t] = p;
    int qs = qx * qx + qy * qy + qz * qz + qw * qw;
#pragma unroll
    for (int off = 32; off > 0; off >>= 1) qs += __shfl_xor(qs, off);
    if ((t & 63) == 0) wqs[t >> 6] = qs;
    __syncthreads();
    if (t == 0) {
        const int qtot = max(wqs[0] + wqs[1] + wqs[2] + wqs[3], 1);
        sinv[row] = 1.0f / sqrtf((float)qtot);
        rowmax[row] = 0u;
    }
}

// ---- simmax: i8, m97 128^2 single-buffer structure, STRIP-ORDERED traversal.
// Tile order: strips of SW=16 jt-columns; within a strip, it outer / jt inner.
// The strip's 16 B-panels (2 MB) stay L2-resident; each A-panel is read once
// per strip and reused for up to 16 consecutive tiles; rowmax/colmax atomics
// hit a small hot window. XCD chunking (8 x 1032) on top of the strip order.

__global__ __launch_bounds__(256, 4)
void simmax_kernel(const signed char* __restrict__ xq,
                   const float* __restrict__ sinv,
                   unsigned* __restrict__ rowmax) {
    // bijective XCD-chunked swizzle (8256 = 8 * 1032)
    const int bid = blockIdx.x;
    int rem = (bid & 7) * (NBLK / 8) + (bid >> 3);
    // strip-order decode: strip s has 256*s + 136 tiles
    int s = 0;
    for (;;) {
        const int sz = 256 * s + 136;
        if (rem < sz) break;
        rem -= sz;
        ++s;
    }
    int it, jt;
    const int full = 256 * s;            // tiles with it < 16s (full width 16)
    if (rem < full) {
        it = rem >> 4;
        jt = SW * s + (rem & 15);
    } else {
        int r2 = rem - full;
        int d = 0;
        while (r2 >= SW - d) { r2 -= SW - d; ++d; }
        it = SW * s + d;
        jt = it + r2;
    }
    const bool diag = (jt == it);
    const int rowBase = it * 128;
    const int colBase = jt * 128;

    __shared__ __align__(16) char lds[2][128][128];  // [A/B][row][128 B] = 32 KiB

    const int t    = threadIdx.x;                    // 256 = 4 waves
    const int lane = t & 63;
    const int wid  = t >> 6;
    const int wr2  = wid >> 1;     // 0..1 (M)
    const int wc2  = wid & 1;      // 0..1 (N)
    const int l15  = lane & 15;
    const int hi   = lane >> 4;

    // staging: chunk c = j*256 + t (j=0..7); op = c>>10 (A/B); cc = c&1023;
    // row = cc>>3, ch = cc&7. LDS dest LINEAR (c*16 B); SOURCE chunk
    // pre-swizzled (ch ^ (row&7)) so the swizzled ds_read finds it (rule #21).
    const signed char* srcp[8];
#pragma unroll
    for (int j = 0; j < 8; ++j) {
        const int c   = j * 256 + t;
        const int op  = c >> 10;
        const int cc  = c & 1023;
        const int row = cc >> 3;
        const int ch  = cc & 7;
        const int gr  = (op ? colBase : rowBase) + row;
        srcp[j] = xq + (size_t)gr * DIM + (ch ^ (row & 7)) * 16;
    }

    i32x4 acc[4][4];
#pragma unroll
    for (int m = 0; m < 4; ++m)
#pragma unroll
        for (int n = 0; n < 4; ++n)
            acc[m][n] = (i32x4){0, 0, 0, 0};

    char* ldsb = &lds[0][0][0];

    for (int kt = 0; kt < NT; ++kt) {
        __syncthreads();               // previous tile's compute done
#pragma unroll
        for (int j = 0; j < 8; ++j) {
            __builtin_amdgcn_global_load_lds(
                (const __attribute__((address_space(1))) void*)srcp[j],
                (__attribute__((address_space(3))) void*)(ldsb + (j * 256 + wid * 64) * 16),
                16, 0, 0);
            srcp[j] += 128;            // next 128-elem i8 K-tile
        }
        __syncthreads();               // drains vmcnt(0): staged data visible

        i32x4 af[4][2], bf[4][2];
#pragma unroll
        for (int m = 0; m < 4; ++m)
#pragma unroll
            for (int kk = 0; kk < 2; ++kk) {
                const int row = wr2 * 64 + m * 16 + l15;
                const int chn = (kk * 4 + hi) ^ (row & 7);
                af[m][kk] = *(const i32x4*)(&lds[0][0][0] + row * 128 + chn * 16);
            }
#pragma unroll
        for (int n = 0; n < 4; ++n)
#pragma unroll
            for (int kk = 0; kk < 2; ++kk) {
                const int row = wc2 * 64 + n * 16 + l15;
                const int chn = (kk * 4 + hi) ^ (row & 7);
                bf[n][kk] = *(const i32x4*)(&lds[1][0][0] + row * 128 + chn * 16);
            }
#pragma unroll
        for (int m = 0; m < 4; ++m)
#pragma unroll
            for (int n = 0; n < 4; ++n)
#pragma unroll
                for (int kk = 0; kk < 2; ++kk)
                    acc[m][n] = __builtin_amdgcn_mfma_i32_16x16x64_i8(
                        af[m][kk], bf[n][kk], acc[m][n], 0, 0, 0);
    }

    // ---- epilogue: scaled tile max reduction ----
    // C/D layout: col = lane&15, row = (lane>>4)*4 + reg  [m89/m91, dtype-indep]
    const int g  = lane >> 4;
    const int cl = lane & 15;

    // column scales (lane's 4 cols) and row scales (lane's 16 rows)
    float scl_col[4];
#pragma unroll
    for (int n = 0; n < 4; ++n)
        scl_col[n] = sinv[colBase + wc2 * 64 + n * 16 + cl];
    float srow[4][4];
#pragma unroll
    for (int m = 0; m < 4; ++m)
#pragma unroll
        for (int r = 0; r < 4; ++r)
            srow[m][r] = sinv[rowBase + wr2 * 64 + m * 16 + g * 4 + r];

    // row-direction: rowmax[i] takes max_j (s_j * d_ij); s_i applied in finalize
#pragma unroll
    for (int m = 0; m < 4; ++m)
#pragma unroll
        for (int r = 0; r < 4; ++r) {
            const int grow = wr2 * 64 + m * 16 + g * 4 + r;
            float v = -1e30f;
#pragma unroll
            for (int n = 0; n < 4; ++n) {
                const int gcol = wc2 * 64 + n * 16 + cl;
                float f = (float)acc[m][n][r] * scl_col[n];
                if (diag && grow == gcol) f = -1e30f;   // exclude self-sim
                v = fmaxf(v, f);
            }
            v = fmaxf(v, __shfl_xor(v, 1));
            v = fmaxf(v, __shfl_xor(v, 2));
            v = fmaxf(v, __shfl_xor(v, 4));
            v = fmaxf(v, __shfl_xor(v, 8));
            if (cl == 0) atomicMax(rowmax + rowBase + grow, fkey(v));
        }

    // col-direction (transpose contribution): max_i (s_i * d_ij); skip on diag
    if (!diag) {
#pragma unroll
        for (int n = 0; n < 4; ++n) {
            float v = -1e30f;
#pragma unroll
            for (int m = 0; m < 4; ++m)
#pragma unroll
                for (int r = 0; r < 4; ++r)
                    v = fmaxf(v, (float)acc[m][n][r] * srow[m][r]);
            v = fmaxf(v, __shfl_xor(v, 16));
            v = fmaxf(v, __shfl_xor(v, 32));
            if (g == 0) {
                const int gcol = colBase + wc2 * 64 + n * 16 + cl;
                atomicMax(rowmax + gcol, fkey(v));
            }
        }
    }
}

__global__ void finalize_kernel(const unsigned* __restrict__ rowmax,
                                const float* __restrict__ sinv,
                                float* __restrict__ out) {
    const int t = threadIdx.x;
    float s = 0.f;
    for (int r = t; r < NROWS; r += 256) {
        const float m = fminf(sinv[r] * funkey(rowmax[r]), 1.0f);   // cos, clamp
        s += logf(2.0f - 2.0f * m + 1e-8f);
    }
#pragma unroll
    for (int off = 32; off > 0; off >>= 1) s += __shfl_xor(s, off);
    __shared__ float ws[4];
    if ((t & 63) == 0) ws[t >> 6] = s;
    __syncthreads();
    if (t == 0) out[0] = -0.5f * (ws[0] + ws[1] + ws[2] + ws[3]) / (float)NROWS;
}

extern "C" void kernel_launch(void* const* d_in, const int* in_sizes, int n_in,
                              void* d_out, int out_size, void* d_ws, size_t ws_size,
                              hipStream_t stream) {
    const float* x = (const float*)d_in[0];
    signed char* xq = (signed char*)d_ws;                                // 16 MB
    float* sinv = (float*)((char*)d_ws + (size_t)NROWS * DIM);           // 64 KB
    unsigned* rowmax = (unsigned*)((char*)d_ws + (size_t)NROWS * DIM + NROWS * sizeof(float));
    float* out = (float*)d_out;

    normalize_rows<<<NROWS, 256, 0, stream>>>(x, xq, sinv, rowmax);
    simmax_kernel<<<NBLK, 256, 0, stream>>>(xq, sinv, rowmax);
    finalize_kernel<<<1, 256, 0, stream>>>(rowmax, sinv, out);
}